// Round 1
// baseline (154.191 us; speedup 1.0000x reference)
//
#include <hip/hip_runtime.h>
#include <math.h>

#define LMAX 10
#define NCOL 121            // (LMAX+1)^2
#define PTS_PER_BLK 64
#define LDS_STRIDE 65       // pad 64->65: epilogue read bank = (j+p)%32, conflict-free

struct KTab { float k[66]; };   // K(l,m)*[sqrt(2) if m>0], index tri(l)+m

__global__ __launch_bounds__(256)
void sh_kernel(const float* __restrict__ in, float* __restrict__ out,
               int n, KTab kt) {
    __shared__ float lds[NCOL * LDS_STRIDE];

    const int p = threadIdx.x & 63;     // local point
    const int s = threadIdx.x >> 6;     // m-split (uniform per wave)
    const long long gp = (long long)blockIdx.x * PTS_PER_BLK + p;

    if (gp < n) {
        const float lon = in[gp * 3 + 0];
        const float lat = in[gp * 3 + 1];
        const float r   = in[gp * 3 + 2];

        const float DEG2RAD = 0.017453292519943295f;
        const float PI_F    = 3.14159265358979323846f;

        float phi   = (lon + 180.0f) * DEG2RAD;
        float theta = (90.0f - lat) * DEG2RAD;
        theta = fminf(fmaxf(theta, 1e-7f), PI_F - 1e-7f);
        float x = cosf(theta);
        x = fminf(fmaxf(x, -1.0f + 1e-7f), 1.0f - 1e-7f);
        float somx2 = sqrtf(fmaxf((1.0f - x) * (1.0f + x), 0.0f));
        float rf = 6371000.0f / r;

        for (int m = s; m <= LMAX; m += 4) {
            // pmm = (-1)^m (2m-1)!! * somx2^m   (reference's loop, verbatim in fp32)
            float pmm = 1.0f, fct = 1.0f;
            for (int i = 1; i <= m; ++i) { pmm *= -fct * somx2; fct += 2.0f; }

            float cm = 1.0f, sm = 0.0f;
            if (m > 0) sincosf((float)m * phi, &sm, &cm);

            float rfl = 1.0f;                       // rf^l, start at l=m
            for (int i = 0; i < m; ++i) rfl *= rf;

            // emit l = m
            {
                float v = kt.k[m * (m + 1) / 2 + m] * pmm * rfl;
                int jb = m * m + m;                 // l^2 + l
                if (m == 0) lds[jb * LDS_STRIDE + p] = v;
                else {
                    lds[(jb + m) * LDS_STRIDE + p] = v * cm;
                    lds[(jb - m) * LDS_STRIDE + p] = v * sm;
                }
            }
            if (m < LMAX) {
                float pm1 = pmm;
                float pcur = x * (2.0f * m + 1.0f) * pmm;
                rfl *= rf;
                {
                    int l = m + 1;
                    float v = kt.k[l * (l + 1) / 2 + m] * pcur * rfl;
                    int jb = l * l + l;
                    if (m == 0) lds[jb * LDS_STRIDE + p] = v;
                    else {
                        lds[(jb + m) * LDS_STRIDE + p] = v * cm;
                        lds[(jb - m) * LDS_STRIDE + p] = v * sm;
                    }
                }
                for (int ll = m + 2; ll <= LMAX; ++ll) {
                    float pll = ((2.0f * ll - 1.0f) * x * pcur
                                 - ((float)(ll + m) - 1.0f) * pm1) / (float)(ll - m);
                    pm1 = pcur; pcur = pll;
                    rfl *= rf;
                    float v = kt.k[ll * (ll + 1) / 2 + m] * pcur * rfl;
                    int jb = ll * ll + ll;
                    if (m == 0) lds[jb * LDS_STRIDE + p] = v;
                    else {
                        lds[(jb + m) * LDS_STRIDE + p] = v * cm;
                        lds[(jb - m) * LDS_STRIDE + p] = v * sm;
                    }
                }
            }
        }
    }
    __syncthreads();

    // coalesced epilogue: dump the [64 points][121 cols] tile linearly
    const long long base = (long long)blockIdx.x * (PTS_PER_BLK * NCOL);
    const long long lim  = (long long)n * NCOL;
    for (int f = threadIdx.x; f < PTS_PER_BLK * NCOL; f += 256) {
        long long g = base + f;
        if (g < lim) {
            int pp = f / NCOL;
            int j  = f - pp * NCOL;
            out[g] = lds[j * LDS_STRIDE + pp];
        }
    }
}

extern "C" void kernel_launch(void* const* d_in, const int* in_sizes, int n_in,
                              void* d_out, int out_size, void* d_ws, size_t ws_size,
                              hipStream_t stream) {
    const float* in = (const float*)d_in[0];
    float* out = (float*)d_out;
    const int n = in_sizes[0] / 3;

    // K(l,m) = sqrt((2l+1) (l-m)! / (l+m)!), * sqrt(2) for m>0 (fourpi renorm folds out)
    KTab kt;
    double fact[2 * LMAX + 1];
    fact[0] = 1.0;
    for (int i = 1; i <= 2 * LMAX; ++i) fact[i] = fact[i - 1] * (double)i;
    for (int l = 0; l <= LMAX; ++l) {
        for (int m = 0; m <= l; ++m) {
            double k = sqrt((2.0 * l + 1.0) * fact[l - m] / fact[l + m]);
            if (m > 0) k *= sqrt(2.0);
            kt.k[l * (l + 1) / 2 + m] = (float)k;
        }
    }

    const int blocks = (n + PTS_PER_BLK - 1) / PTS_PER_BLK;
    sh_kernel<<<blocks, 256, 0, stream>>>(in, out, n, kt);
}

// Round 2
// 96.651 us; speedup vs baseline: 1.5953x; 1.5953x over previous
//
#include <hip/hip_runtime.h>
#include <math.h>

#define LMAX 10
#define NCOL 121            // (LMAX+1)^2
#define PPB  64             // points per block

typedef float f4_t __attribute__((ext_vector_type(4)));

struct Tab {
    float K[66];   // K(l,m) (* sqrt2 for m>0), index l(l+1)/2+m
    float A[66];   // (2l-1)/(l-m)    for l>=m+2
    float B[66];   // (l+m-1)/(l-m)   for l>=m+2
};

// Emit chain for fixed M: P(l,M) for l=M..LMAX, scaled by K * rf^l (and cos/sin(M phi))
template<int M>
__device__ __forceinline__ void chain(const Tab& t, float* __restrict__ row,
                                      float pmm, float rfm, float rf, float x,
                                      float cm, float sm) {
    // l = M
    {
        float v = t.K[M * (M + 1) / 2 + M] * pmm * rfm;
        if constexpr (M == 0) row[0] = v;
        else { row[M * M + 2 * M] = v * cm; row[M * M] = v * sm; }
    }
    if constexpr (M < LMAX) {
        float p0 = pmm;
        float p1 = x * (float)(2 * M + 1) * pmm;
        float rfl = rfm * rf;
        {
            constexpr int L = M + 1;
            float v = t.K[L * (L + 1) / 2 + M] * p1 * rfl;
            if constexpr (M == 0) row[L * L + L] = v;
            else { row[L * L + L + M] = v * cm; row[L * L + L - M] = v * sm; }
        }
#pragma unroll
        for (int ll = M + 2; ll <= LMAX; ++ll) {
            int ti = ll * (ll + 1) / 2 + M;
            float p2 = t.A[ti] * x * p1 - t.B[ti] * p0;
            p0 = p1; p1 = p2;
            rfl *= rf;
            float v = t.K[ti] * p1 * rfl;
            int jb = ll * ll + ll;
            if constexpr (M == 0) row[jb] = v;
            else { row[jb + M] = v * cm; row[jb - M] = v * sm; }
        }
    }
}

__global__ __launch_bounds__(256)
void sh_kernel(const float* __restrict__ in, float* __restrict__ out,
               int n, Tab t) {
    __shared__ f4_t lds4[PPB * NCOL / 4];          // [point][j], 16B aligned, == out layout
    float* lds = (float*)lds4;

    const int p = threadIdx.x & 63;                // local point
    const int s = threadIdx.x >> 6;                // m-group (wave-uniform)
    const long long gp = (long long)blockIdx.x * PPB + p;

    if (gp < n) {
        const float lon = in[gp * 3 + 0];
        const float lat = in[gp * 3 + 1];
        const float r   = in[gp * 3 + 2];

        const float D2R  = 0.017453292519943295f;
        const float PI_F = 3.14159265358979323846f;

        float phi   = (lon + 180.0f) * D2R;
        float theta = fminf(fmaxf((90.0f - lat) * D2R, 1e-7f), PI_F - 1e-7f);
        float x = __cosf(theta);
        x = fminf(fmaxf(x, -1.0f + 1e-7f), 1.0f - 1e-7f);
        float somx2 = sqrtf(fmaxf((1.0f - x) * (1.0f + x), 0.0f));
        float rf  = 6371000.0f / r;
        float rf2 = rf * rf;
        float rf4 = rf2 * rf2;

        float c1, s1;
        __sincosf(phi, &s1, &c1);
        float c2 = c1 * c1 - s1 * s1, s2 = 2.0f * c1 * s1;
        float c4 = c2 * c2 - s2 * s2, s4 = 2.0f * c2 * s2;

        float sx2 = somx2 * somx2;
        float sx4 = sx2 * sx2;

        float* row = lds + p * NCOL;

#define ROT(cm, sm) { float cn = cm * c4 - sm * s4; sm = sm * c4 + cm * s4; cm = cn; }

        switch (s) {
        case 0: {
            float pmm = 1.0f, rfm = 1.0f, cm = 1.0f, sm = 0.0f;
            chain<0>(t, row, pmm, rfm, rf, x, cm, sm);
            pmm *= 105.0f * sx4;   rfm *= rf4; ROT(cm, sm);      // 1*3*5*7
            chain<4>(t, row, pmm, rfm, rf, x, cm, sm);
            pmm *= 19305.0f * sx4; rfm *= rf4; ROT(cm, sm);      // 9*11*13*15
            chain<8>(t, row, pmm, rfm, rf, x, cm, sm);
        } break;
        case 1: {
            float pmm = -somx2, rfm = rf, cm = c1, sm = s1;
            chain<1>(t, row, pmm, rfm, rf, x, cm, sm);
            pmm *= 945.0f * sx4;   rfm *= rf4; ROT(cm, sm);      // 3*5*7*9
            chain<5>(t, row, pmm, rfm, rf, x, cm, sm);
            pmm *= 36465.0f * sx4; rfm *= rf4; ROT(cm, sm);      // 11*13*15*17
            chain<9>(t, row, pmm, rfm, rf, x, cm, sm);
        } break;
        case 2: {
            float pmm = 3.0f * sx2, rfm = rf2, cm = c2, sm = s2;
            chain<2>(t, row, pmm, rfm, rf, x, cm, sm);
            pmm *= 3465.0f * sx4;  rfm *= rf4; ROT(cm, sm);      // 5*7*9*11
            chain<6>(t, row, pmm, rfm, rf, x, cm, sm);
            pmm *= 62985.0f * sx4; rfm *= rf4; ROT(cm, sm);      // 13*15*17*19
            chain<10>(t, row, pmm, rfm, rf, x, cm, sm);
        } break;
        default: {
            float pmm = -15.0f * sx2 * somx2, rfm = rf2 * rf;
            float cm = c2 * c1 - s2 * s1, sm = s2 * c1 + c2 * s1;
            chain<3>(t, row, pmm, rfm, rf, x, cm, sm);
            pmm *= 9009.0f * sx4;  rfm *= rf4; ROT(cm, sm);      // 7*9*11*13
            chain<7>(t, row, pmm, rfm, rf, x, cm, sm);
        } break;
        }
#undef ROT
    }
    __syncthreads();

    // Epilogue: tile is already in output order -> pure linear copy, float4-wide
    const long long base4 = (long long)blockIdx.x * (PPB * NCOL / 4);
    const long long lim4  = ((long long)n * NCOL + 3) / 4;
    f4_t* __restrict__ out4 = (f4_t*)out;
#pragma unroll
    for (int f4 = threadIdx.x; f4 < PPB * NCOL / 4; f4 += 256) {
        long long g4 = base4 + f4;
        if (g4 < lim4) __builtin_nontemporal_store(lds4[f4], &out4[g4]);
    }
}

extern "C" void kernel_launch(void* const* d_in, const int* in_sizes, int n_in,
                              void* d_out, int out_size, void* d_ws, size_t ws_size,
                              hipStream_t stream) {
    const float* in = (const float*)d_in[0];
    float* out = (float*)d_out;
    const int n = in_sizes[0] / 3;

    Tab t;
    double fact[2 * LMAX + 1];
    fact[0] = 1.0;
    for (int i = 1; i <= 2 * LMAX; ++i) fact[i] = fact[i - 1] * (double)i;
    for (int l = 0; l <= LMAX; ++l) {
        for (int m = 0; m <= l; ++m) {
            int ti = l * (l + 1) / 2 + m;
            double k = sqrt((2.0 * l + 1.0) * fact[l - m] / fact[l + m]);
            if (m > 0) k *= sqrt(2.0);
            t.K[ti] = (float)k;
            if (l >= m + 2) {
                t.A[ti] = (float)((2.0 * l - 1.0) / (double)(l - m));
                t.B[ti] = (float)(((double)(l + m) - 1.0) / (double)(l - m));
            } else {
                t.A[ti] = 0.0f; t.B[ti] = 0.0f;
            }
        }
    }

    const int blocks = (n + PPB - 1) / PPB;
    sh_kernel<<<blocks, 256, 0, stream>>>(in, out, n, t);
}

// Round 3
// 94.771 us; speedup vs baseline: 1.6270x; 1.0198x over previous
//
#include <hip/hip_runtime.h>
#include <math.h>

#define LMAX 10
#define NCOL 121            // (LMAX+1)^2
#define PPB  64             // points per block
#define TILE4 (PPB * NCOL / 4)   // 1936 float4 per block tile

typedef float f4_t __attribute__((ext_vector_type(4)));

struct Tab {
    float K[66];   // K(l,m) (* sqrt2 for m>0), index l(l+1)/2+m
    float A[66];   // (2l-1)/(l-m)    for l>=m+2
    float B[66];   // (l+m-1)/(l-m)   for l>=m+2
};

// Emit chain for fixed M: P(l,M) for l=M..LMAX, scaled by K * rf^l (and cos/sin(M phi))
template<int M>
__device__ __forceinline__ void chain(const Tab& t, float* __restrict__ row,
                                      float pmm, float rfm, float rf, float x,
                                      float cm, float sm) {
    {
        float v = t.K[M * (M + 1) / 2 + M] * pmm * rfm;
        if constexpr (M == 0) row[0] = v;
        else { row[M * M + 2 * M] = v * cm; row[M * M] = v * sm; }
    }
    if constexpr (M < LMAX) {
        float p0 = pmm;
        float p1 = x * (float)(2 * M + 1) * pmm;
        float rfl = rfm * rf;
        {
            constexpr int L = M + 1;
            float v = t.K[L * (L + 1) / 2 + M] * p1 * rfl;
            if constexpr (M == 0) row[L * L + L] = v;
            else { row[L * L + L + M] = v * cm; row[L * L + L - M] = v * sm; }
        }
#pragma unroll
        for (int ll = M + 2; ll <= LMAX; ++ll) {
            int ti = ll * (ll + 1) / 2 + M;
            float p2 = t.A[ti] * x * p1 - t.B[ti] * p0;
            p0 = p1; p1 = p2;
            rfl *= rf;
            float v = t.K[ti] * p1 * rfl;
            int jb = ll * ll + ll;
            if constexpr (M == 0) row[jb] = v;
            else { row[jb + M] = v * cm; row[jb - M] = v * sm; }
        }
    }
}

template<bool FULL>
__global__ __launch_bounds__(256)
void sh_kernel(const float* __restrict__ in, float* __restrict__ out,
               int n, int blk_off, Tab t) {
    __shared__ f4_t lds4[TILE4];               // [point][j], == output layout
    float* lds = (float*)lds4;

    const int bid = blockIdx.x + blk_off;
    const int p = threadIdx.x & 63;            // local point
    const int s = threadIdx.x >> 6;            // m-group (wave-uniform)
    const long long gp = (long long)bid * PPB + p;

    if (FULL || gp < n) {
        const float lon = in[gp * 3 + 0];
        const float lat = in[gp * 3 + 1];
        const float r   = in[gp * 3 + 2];

        const float D2R  = 0.017453292519943295f;
        const float PI_F = 3.14159265358979323846f;

        float phi   = (lon + 180.0f) * D2R;
        float theta = fminf(fmaxf((90.0f - lat) * D2R, 1e-7f), PI_F - 1e-7f);
        float x = __cosf(theta);
        x = fminf(fmaxf(x, -1.0f + 1e-7f), 1.0f - 1e-7f);
        float somx2 = sqrtf(fmaxf((1.0f - x) * (1.0f + x), 0.0f));
        float rf  = 6371000.0f / r;
        float rf2 = rf * rf;
        float rf3 = rf2 * rf;
        float rf5 = rf3 * rf2;

        float c1, s1;
        __sincosf(phi, &s1, &c1);
        float c2 = c1 * c1 - s1 * s1, s2 = 2.0f * c1 * s1;
        float c3 = c2 * c1 - s2 * s1, s3 = s2 * c1 + c2 * s1;
        float c4 = c2 * c2 - s2 * s2, s4 = 2.0f * c2 * s2;
        float c5 = c4 * c1 - s4 * s1, s5 = s4 * c1 + c4 * s1;

        float sx2 = somx2 * somx2;
        float sx3 = sx2 * somx2;
        float sx5 = sx3 * sx2;

        float* row = lds + p * NCOL;

#define ROT(cm, sm, ck, sk) { float cn = cm * ck - sm * sk; sm = sm * ck + cm * sk; cm = cn; }

        // m-sets balanced by chain length: {0,5,10}=18, {1,6,9}=17, {2,7,8}=16, {3,4}=15
        switch (s) {
        case 0: {
            float pmm = 1.0f, rfm = 1.0f, cm = 1.0f, sm = 0.0f;
            chain<0>(t, row, pmm, rfm, rf, x, cm, sm);
            pmm *= -945.0f    * sx5; rfm *= rf5; ROT(cm, sm, c5, s5);   // 1*3*5*7*9
            chain<5>(t, row, pmm, rfm, rf, x, cm, sm);
            pmm *= -692835.0f * sx5; rfm *= rf5; ROT(cm, sm, c5, s5);   // 11*13*15*17*19
            chain<10>(t, row, pmm, rfm, rf, x, cm, sm);
        } break;
        case 1: {
            float pmm = -somx2, rfm = rf, cm = c1, sm = s1;
            chain<1>(t, row, pmm, rfm, rf, x, cm, sm);
            pmm *= -10395.0f * sx5; rfm *= rf5; ROT(cm, sm, c5, s5);    // 3*5*7*9*11
            chain<6>(t, row, pmm, rfm, rf, x, cm, sm);
            pmm *= -3315.0f  * sx3; rfm *= rf3; ROT(cm, sm, c3, s3);    // 13*15*17
            chain<9>(t, row, pmm, rfm, rf, x, cm, sm);
        } break;
        case 2: {
            float pmm = 3.0f * sx2, rfm = rf2, cm = c2, sm = s2;
            chain<2>(t, row, pmm, rfm, rf, x, cm, sm);
            pmm *= -45045.0f * sx5; rfm *= rf5; ROT(cm, sm, c5, s5);    // 5*7*9*11*13
            chain<7>(t, row, pmm, rfm, rf, x, cm, sm);
            pmm *= -15.0f * somx2;  rfm *= rf;  ROT(cm, sm, c1, s1);    // 15
            chain<8>(t, row, pmm, rfm, rf, x, cm, sm);
        } break;
        default: {
            float pmm = -15.0f * sx3, rfm = rf3, cm = c3, sm = s3;
            chain<3>(t, row, pmm, rfm, rf, x, cm, sm);
            pmm *= -7.0f * somx2; rfm *= rf; ROT(cm, sm, c1, s1);       // 7
            chain<4>(t, row, pmm, rfm, rf, x, cm, sm);
        } break;
        }
#undef ROT
    }
    __syncthreads();

    // Epilogue: tile already in output order -> pure linear float4 copy
    f4_t* __restrict__ dst = (f4_t*)out + (long long)bid * TILE4;
    if (FULL) {
#pragma unroll
        for (int k = 0; k < 7; ++k)
            __builtin_nontemporal_store(lds4[threadIdx.x + k * 256],
                                        &dst[threadIdx.x + k * 256]);
        if (threadIdx.x < TILE4 - 7 * 256)   // 1936 - 1792 = 144
            __builtin_nontemporal_store(lds4[threadIdx.x + 7 * 256],
                                        &dst[threadIdx.x + 7 * 256]);
    } else {
        const long long lim4 = ((long long)n * NCOL + 3) / 4;
        const long long base4 = (long long)bid * TILE4;
        for (int f = threadIdx.x; f < TILE4; f += 256) {
            if (base4 + f < lim4)
                __builtin_nontemporal_store(lds4[f], &dst[f]);
        }
    }
}

extern "C" void kernel_launch(void* const* d_in, const int* in_sizes, int n_in,
                              void* d_out, int out_size, void* d_ws, size_t ws_size,
                              hipStream_t stream) {
    const float* in = (const float*)d_in[0];
    float* out = (float*)d_out;
    const int n = in_sizes[0] / 3;

    Tab t;
    double fact[2 * LMAX + 1];
    fact[0] = 1.0;
    for (int i = 1; i <= 2 * LMAX; ++i) fact[i] = fact[i - 1] * (double)i;
    for (int l = 0; l <= LMAX; ++l) {
        for (int m = 0; m <= l; ++m) {
            int ti = l * (l + 1) / 2 + m;
            double k = sqrt((2.0 * l + 1.0) * fact[l - m] / fact[l + m]);
            if (m > 0) k *= sqrt(2.0);
            t.K[ti] = (float)k;
            if (l >= m + 2) {
                t.A[ti] = (float)((2.0 * l - 1.0) / (double)(l - m));
                t.B[ti] = (float)(((double)(l + m) - 1.0) / (double)(l - m));
            } else {
                t.A[ti] = 0.0f; t.B[ti] = 0.0f;
            }
        }
    }

    const int full_blocks = n / PPB;
    const int tail_pts    = n - full_blocks * PPB;
    if (full_blocks > 0)
        sh_kernel<true><<<full_blocks, 256, 0, stream>>>(in, out, n, 0, t);
    if (tail_pts > 0)
        sh_kernel<false><<<1, 256, 0, stream>>>(in, out, n, full_blocks, t);
}